// Round 6
// baseline (338.420 us; speedup 1.0000x reference)
//
#include <hip/hip_runtime.h>
#include <math.h>

#define SUM_H 224
#define SUM_W 221
#define TROW  672   // floats per gene table row

// table layout (float offsets inside a gene row); all 16B-aligned
#define OBL0 0
#define OA0  128
#define OB0  256
#define OBL1 384
#define OA1  448
#define OB1  512
#define OBL2 576
#define OA2  608
#define OB2  640

typedef float f32x4 __attribute__((ext_vector_type(4)));
typedef float f32x2 __attribute__((ext_vector_type(2)));

__device__ __forceinline__ f32x4 ldnt4(const float* p) {
    return __builtin_nontemporal_load((const f32x4*)p);
}
__device__ __forceinline__ f32x2 ldnt2(const float* p) {
    return __builtin_nontemporal_load((const f32x2*)p);
}

// ---------------------------------------------------------------------------
// Kernel 1: per selected gene, build: bin edges bl (leading 0, last forced 1),
// A[k] = 0.5*width[k]*exp(uh[k]), B[k] = 0.5*width[k]*exp(uh[k+1]).
// Pad entries (index n-1 of A/B) are 0. One wave per gene.
// ---------------------------------------------------------------------------
__global__ __launch_bounds__(64) void gene_tables_kernel(
    const float* __restrict__ heights_weight,
    const float* __restrict__ widths_weight,
    const int*   __restrict__ genes_oi,
    float* __restrict__ tbl,
    int n_genes)
{
    int g = blockIdx.x;
    if (g >= n_genes) return;
    int gi = genes_oi[g];
    int l  = threadIdx.x;

    const float* wsrc = widths_weight  + (size_t)gi * SUM_W;
    const float* hsrc = heights_weight + (size_t)gi * SUM_H;
    float*       row  = tbl + (size_t)g * TROW;

    const int ns[3]   = {128, 64, 32};
    const int woff[3] = {0, 127, 190};
    const int hoff[3] = {0, 128, 192};
    const int obl[3]  = {OBL0, OBL1, OBL2};
    const int oa[3]   = {OA0, OA1, OA2};
    const int ob[3]   = {OB0, OB1, OB2};

    for (int lev = 0; lev < 3; lev++) {
        int m  = ns[lev] - 1;             // number of widths
        int j0 = 2 * l, j1 = 2 * l + 1;   // lane l owns width elems 2l, 2l+1
        float u0 = (j0 < m) ? wsrc[woff[lev] + j0] : -1e30f;
        float u1 = (j1 < m) ? wsrc[woff[lev] + j1] : -1e30f;
        float mx = fmaxf(u0, u1);
        #pragma unroll
        for (int msk = 32; msk >= 1; msk >>= 1)
            mx = fmaxf(mx, __shfl_xor(mx, msk, 64));
        float e0 = (j0 < m) ? __expf(u0 - mx) : 0.f;
        float e1 = (j1 < m) ? __expf(u1 - mx) : 0.f;
        float local = e0 + e1;
        float incl  = local;
        #pragma unroll
        for (int off = 1; off < 64; off <<= 1) {
            float t = __shfl_up(incl, off, 64);
            if (l >= off) incl += t;
        }
        float total = __shfl(incl, 63, 64);
        float inv   = 1.0f / total;
        float w0    = e0 * inv;
        float w1    = e1 * inv;
        float excl  = incl - local;
        float c0 = (excl + e0) * inv;
        float c1 = (excl + e0 + e1) * inv;
        // bin edges
        if (j0 <= m - 2) row[obl[lev] + j0 + 1] = c0;
        if (j1 <= m - 2) row[obl[lev] + j1 + 1] = c1;
        // A/B  (uh[j+1] valid up to j = m-1 since uh has m+1 entries)
        float h0 = (j0 < m) ? __expf(hsrc[hoff[lev] + j0])     : 0.f;
        float h1 = (j0 < m) ? __expf(hsrc[hoff[lev] + j0 + 1]) : 0.f;
        float h2 = (j1 < m) ? __expf(hsrc[hoff[lev] + j1 + 1]) : 0.f;
        if (j0 < m) { row[oa[lev] + j0] = 0.5f * w0 * h0;  row[ob[lev] + j0] = 0.5f * w0 * h1; }
        if (j1 < m) { row[oa[lev] + j1] = 0.5f * w1 * h1;  row[ob[lev] + j1] = 0.5f * w1 * h2; }
        if (l == 0) {
            row[obl[lev]]     = 0.0f;
            row[obl[lev] + m] = 1.0f;
            row[oa[lev]  + m] = 0.0f;   // pad
            row[ob[lev]  + m] = 0.0f;   // pad
        }
    }
}

// ---------------------------------------------------------------------------
// DPP 16-lane rotate-reductions (a DPP row == one 16-lane point group).
// Proven in R3/R4.
// ---------------------------------------------------------------------------
template<int CTRL>
__device__ __forceinline__ float dppf(float v) {
    return __builtin_bit_cast(float,
        __builtin_amdgcn_update_dpp(0, __builtin_bit_cast(int, v), CTRL, 0xF, 0xF, true));
}
template<int CTRL>
__device__ __forceinline__ int dppi(int v) {
    return __builtin_amdgcn_update_dpp(0, v, CTRL, 0xF, 0xF, true);
}
__device__ __forceinline__ float row16_sum(float v) {
    v += dppf<0x121>(v); v += dppf<0x122>(v); v += dppf<0x124>(v); v += dppf<0x128>(v);
    return v;
}
__device__ __forceinline__ int row16_sum_i(int v) {
    v += dppi<0x121>(v); v += dppi<0x122>(v); v += dppi<0x124>(v); v += dppi<0x128>(v);
    return v;
}

// ---------------------------------------------------------------------------
// Kernel 2: 16 lanes per point; lane e owns contiguous elems [K*e, K*e+K).
// ---------------------------------------------------------------------------
template<int K>
struct Lvl {
    float bl[K];   // bin edges
    float a[K];    // staged A, then p = A*edh  (= 0.5*w*El raw)
    float b[K];    // staged B, then s = trapezoid mass
    float d[K];    // staged dh
    float bln;     // next lane's bl[0] (junk at e15, masked)
    float inva;    // 1/area (uniform)
};

template<int K>
__device__ __forceinline__ void lvl_finish(int e, Lvl<K>& L)
{
    float ed[K];
    #pragma unroll
    for (int k = 0; k < K; k++) ed[k] = __expf(L.d[k]);
    float edn = __shfl_down(ed[0], 1, 16);     // junk at e15 (finite); A/B pad=0 => s=0
    L.bln     = __shfl_down(L.bl[0], 1, 16);   // junk at e15, masked in apply
    #pragma unroll
    for (int k = 0; k < K; k++) L.a[k] *= ed[k];                            // p
    #pragma unroll
    for (int k = 0; k < K - 1; k++) L.b[k] = fmaf(L.b[k], ed[k + 1], L.a[k]); // s
    L.b[K - 1] = fmaf(L.b[K - 1], edn, L.a[K - 1]);
    float lane = 0.f;
    #pragma unroll
    for (int k = 0; k < K; k++) lane += L.b[k];
    L.inva = __builtin_amdgcn_rcpf(row16_sum(lane));
}

template<int N, int K>
__device__ __forceinline__ void lvl_apply(int e, const Lvl<K>& L, float& x, float& prod)
{
    constexpr int LOGK = (K == 8) ? 3 : (K == 4) ? 2 : 1;
    bool c[K];
    #pragma unroll
    for (int k = 0; k < K; k++) c[k] = (x >= L.bl[k]);
    bool not15 = (e != 15);
    bool cn = not15 && (x >= L.bln);

    int   cnt  = 0;
    float part = 0.f;
    #pragma unroll
    for (int k = 0; k < K; k++) cnt += c[k] ? 1 : 0;
    #pragma unroll
    for (int k = 0; k < K - 1; k++) part += c[k + 1] ? L.b[k] : 0.f;
    part += cn ? L.b[K - 1] : 0.f;

    cnt  = row16_sum_i(cnt);
    part = row16_sum(part);

    int idx = cnt - 1;                 // cnt >= 1 since bl[0]=0 <= x
    if (idx > N - 2) idx = N - 2;      // x==1.0; out-clip absorbs part's off-by-one
    const int owner = idx >> LOGK;

    // keep-select: last local slot with edge <= x (owner lane's value == idx's slot)
    float sB = L.bl[0], sB1 = L.bl[1], sP = L.a[0], sS = L.b[0];
    #pragma unroll
    for (int jj = 1; jj < K; jj++) {
        bool  m   = (jj == K - 1) ? (c[jj] && not15) : c[jj];
        float nb1 = (jj == K - 1) ? L.bln : L.bl[jj + 1];
        sB  = m ? L.bl[jj] : sB;
        sB1 = m ? nb1      : sB1;
        sP  = m ? L.a[jj]  : sP;
        sS  = m ? L.b[jj]  : sS;
    }
    float sw = sB1 - sB;

    float inb = __shfl(sB, owner, 16);
    float ww  = __shfl(sw, owner, 16);
    float P   = __shfl(sP, owner, 16);
    float S   = __shfl(sS, owner, 16);

    float dEh   = fmaf(-2.f, P, S);            // 0.5*w*(Er-El)
    float rw    = __builtin_amdgcn_rcpf(ww);
    float alpha = (x - inb) * rw;
    float poly  = fmaf(fmaf(dEh, alpha, P + P), alpha, part);
    x = __builtin_amdgcn_fmed3f(poly * L.inva, 0.0f, 1.0f);
    prod *= fmaf(alpha, dEh, P) * (rw * L.inva);   // 0.5*(El+alpha*dE)/area
}

__global__ __launch_bounds__(256) void spline_kernel(
    const float* __restrict__ x_in,
    const float* __restrict__ delta,
    const int*   __restrict__ lgx,
    const float* __restrict__ tbl,
    float* __restrict__ out,
    float* __restrict__ lad_out,
    int n_points)
{
    int tid = blockIdx.x * blockDim.x + threadIdx.x;
    int p = tid >> 4;
    int e = tid & 15;
    if (p >= n_points) return;

    const float* dh = delta + (size_t)p * SUM_H;

    Lvl<8> L0; Lvl<4> L1; Lvl<2> L2;
    // delta loads first (independent of the index chain)
    {
        const int j = 8 * e;
        f32x4 d0 = ldnt4(dh + j), d1 = ldnt4(dh + j + 4);
        #pragma unroll
        for (int k = 0; k < 4; k++) { L0.d[k] = d0[k]; L0.d[4 + k] = d1[k]; }
        f32x4 d2 = ldnt4(dh + 128 + 4 * e);
        #pragma unroll
        for (int k = 0; k < 4; k++) L1.d[k] = d2[k];
        f32x2 d3 = ldnt2(dh + 192 + 2 * e);
        L2.d[0] = d3[0]; L2.d[1] = d3[1];
    }
    float x = x_in[p];
    int   g = lgx[p];
    const float* row = tbl + (size_t)g * TROW;

    // table loads
    {
        const int j = 8 * e;
        *(float4*)&L0.bl[0] = *(const float4*)(row + OBL0 + j);
        *(float4*)&L0.bl[4] = *(const float4*)(row + OBL0 + j + 4);
        *(float4*)&L0.a[0]  = *(const float4*)(row + OA0  + j);
        *(float4*)&L0.a[4]  = *(const float4*)(row + OA0  + j + 4);
        *(float4*)&L0.b[0]  = *(const float4*)(row + OB0  + j);
        *(float4*)&L0.b[4]  = *(const float4*)(row + OB0  + j + 4);
        const int j1 = 4 * e;
        *(float4*)&L1.bl[0] = *(const float4*)(row + OBL1 + j1);
        *(float4*)&L1.a[0]  = *(const float4*)(row + OA1  + j1);
        *(float4*)&L1.b[0]  = *(const float4*)(row + OB1  + j1);
        const int j2 = 2 * e;
        *(float2*)&L2.bl[0] = *(const float2*)(row + OBL2 + j2);
        *(float2*)&L2.a[0]  = *(const float2*)(row + OA2  + j2);
        *(float2*)&L2.b[0]  = *(const float2*)(row + OB2  + j2);
    }

    lvl_finish<8>(e, L0);
    lvl_finish<4>(e, L1);
    lvl_finish<2>(e, L2);

    float prod = 1.f;
    lvl_apply<128, 8>(e, L0, x, prod);
    lvl_apply<64,  4>(e, L1, x, prod);
    lvl_apply<32,  2>(e, L2, x, prod);

    if (e == 0) {
        out[p]     = x;
        lad_out[p] = __logf(prod) + 2.0794415416798357f;   // + ln(2^3)
    }
}

extern "C" void kernel_launch(void* const* d_in, const int* in_sizes, int n_in,
                              void* d_out, int out_size, void* d_ws, size_t ws_size,
                              hipStream_t stream)
{
    const float* x        = (const float*)d_in[0];
    const float* delta    = (const float*)d_in[1];
    const float* hw       = (const float*)d_in[2];
    const float* ww       = (const float*)d_in[3];
    const int*   genes_oi = (const int*)  d_in[4];
    const int*   lgx      = (const int*)  d_in[5];

    int n_points   = in_sizes[0];
    int n_genes_oi = in_sizes[4];

    float* tbl = (float*)d_ws;

    hipLaunchKernelGGL(gene_tables_kernel, dim3(n_genes_oi), dim3(64), 0, stream,
                       hw, ww, genes_oi, tbl, n_genes_oi);

    const int threads = 256;
    const int ppb     = threads / 16;
    const int blocks  = (n_points + ppb - 1) / ppb;
    hipLaunchKernelGGL(spline_kernel, dim3(blocks), dim3(threads), 0, stream,
                       x, delta, lgx, tbl,
                       (float*)d_out, (float*)d_out + n_points, n_points);
}